// Round 1
// baseline (753.343 us; speedup 1.0000x reference)
//
#include <hip/hip_runtime.h>
#include <math.h>

#define HEIGHT 300
#define WIDTH  25
#define CH     16
#define BATCH  1024
// bits set at w = 3, 8, 12, 14, 17, 19
#define ROI_MASK 0x000A5108u

// Kernel 1: per-batch inverse L2 norms. One wave (64 lanes) per batch row.
// inv[0..1023]    = 1/sqrt(max(sum t_o[b]^2, 1e-12))
// inv[1024..2047] = 1/sqrt(max(sum s_o[b]^2, 1e-12))
__global__ void __launch_bounds__(64)
norms_kernel(const float* __restrict__ s_o,
             const float* __restrict__ t_o,
             float* __restrict__ inv) {
    const int b = blockIdx.x;
    const int lane = threadIdx.x;

    // t row: 300 elements, lanes stride by 64
    float acc_t = 0.f;
    const float* tr = t_o + b * HEIGHT;
    for (int i = lane; i < HEIGHT; i += 64) {
        float v = tr[i];
        acc_t += v * v;
    }
    // s row: 25 elements
    float acc_s = 0.f;
    if (lane < WIDTH) {
        float v = s_o[b * WIDTH + lane];
        acc_s = v * v;
    }
    // wave-64 butterfly reductions
    #pragma unroll
    for (int off = 32; off > 0; off >>= 1) {
        acc_t += __shfl_down(acc_t, off, 64);
        acc_s += __shfl_down(acc_s, off, 64);
    }
    if (lane == 0) {
        inv[b]         = 1.0f / sqrtf(fmaxf(acc_t, 1e-12f));
        inv[BATCH + b] = 1.0f / sqrtf(fmaxf(acc_s, 1e-12f));
    }
}

// Kernel 2: out[b,h,w,c] = (t_o[b,h]*inv_t[b] * s_o[b,w]*inv_s[b] + roi[w]) * ipt[b,h,w,c]
// One float4 (4 channels) per thread; c=16 -> 4 f4 per (b,h,w).
__global__ void __launch_bounds__(256)
scale_kernel(const float* __restrict__ s_o,
             const float* __restrict__ t_o,
             const float4* __restrict__ ipt,
             const float* __restrict__ inv,
             float4* __restrict__ out) {
    const int n4 = BATCH * HEIGHT * WIDTH * (CH / 4);  // 30,720,000 < 2^31
    int i = blockIdx.x * blockDim.x + threadIdx.x;
    if (i >= n4) return;

    int p  = i >> 2;          // (b,h,w) flat index
    int w  = p % WIDTH;
    int bh = p / WIDTH;
    int h  = bh % HEIGHT;
    int b  = bh / HEIGHT;

    float roi = (float)((ROI_MASK >> w) & 1u);
    float a = (t_o[b * HEIGHT + h] * inv[b]) * (s_o[b * WIDTH + w] * inv[BATCH + b]) + roi;

    float4 v = ipt[i];
    float4 o;
    o.x = v.x * a;
    o.y = v.y * a;
    o.z = v.z * a;
    o.w = v.w * a;
    out[i] = o;
}

extern "C" void kernel_launch(void* const* d_in, const int* in_sizes, int n_in,
                              void* d_out, int out_size, void* d_ws, size_t ws_size,
                              hipStream_t stream) {
    const float* s_o = (const float*)d_in[0];  // [1024, 25]
    const float* t_o = (const float*)d_in[1];  // [1024, 300]
    const float* ipt = (const float*)d_in[2];  // [1024, 300, 25, 16]
    float* out = (float*)d_out;
    float* inv = (float*)d_ws;                 // 2048 floats

    norms_kernel<<<BATCH, 64, 0, stream>>>(s_o, t_o, inv);

    const int n4 = BATCH * HEIGHT * WIDTH * (CH / 4);
    const int blocks = (n4 + 255) / 256;
    scale_kernel<<<blocks, 256, 0, stream>>>(s_o, t_o, (const float4*)ipt, inv,
                                             (float4*)out);
}